// Round 1
// baseline (46390.936 us; speedup 1.0000x reference)
//
#include <hip/hip_runtime.h>
#include <math.h>

#define BB 16
#define CC 192
#define NF 192
#define HH 128
#define WW 128
#define G4 768
#define JT 8   // output channels per block

__device__ __forceinline__ float hsig(float v) {
    float y = fmaf(0.2f, v, 0.5f);
    return fminf(fmaxf(y, 0.f), 1.f);
}

// Build masked input-to-state weights: rows 0..63 keep c<64, rows 64..127 keep c<128.
__global__ void mask_weights(const float* __restrict__ Wf, float* __restrict__ Wm) {
    int idx = blockIdx.x * blockDim.x + threadIdx.x;
    if (idx >= G4 * CC) return;
    int row = idx / CC;
    int c = idx - row * CC;
    int lim = row < 64 ? 64 : (row < 128 ? 128 : 192);
    Wm[idx] = (c < lim) ? Wf[idx] : 0.f;
}

// Broadcast init_c over batch into c_state (ws is poisoned each call).
__global__ void init_c_state(const float* __restrict__ init_c, float* __restrict__ c_state) {
    int idx = blockIdx.x * blockDim.x + threadIdx.x;  // over B*NF*W
    if (idx >= BB * NF * WW) return;
    int jw = idx % (NF * WW);
    c_state[idx] = init_c[jw];
}

// One recurrence step t. Fuses i2s GEMM (masked W) + 3-tap conv over h_{t-1} + LSTM update.
// grid = (NF/JT=24, B=16); block = 128 threads (one per w).
// hprev: base pointer with strides (t==0 -> init_h broadcast, else d_out at row t-1).
__global__ __launch_bounds__(128) void lstm_step(
    const float* __restrict__ x,     // (B,C,H,W)
    const float* __restrict__ Wm,    // (768,192) masked
    const float* __restrict__ U,     // (768,192,3)
    const float* __restrict__ bias,  // (768)
    const float* __restrict__ hprev,
    long hb_stride, long hc_stride,
    float* __restrict__ c_state,     // (B,NF,W)
    float* __restrict__ out,         // (B,NF,H,W)
    int t)
{
    const int w = threadIdx.x;       // 0..127
    const int j0 = blockIdx.x * JT;
    const int b = blockIdx.y;

    float acc[JT][4];
#pragma unroll
    for (int j = 0; j < JT; ++j)
#pragma unroll
        for (int g = 0; g < 4; ++g)
            acc[j][g] = bias[g * NF + j0 + j];

    const float* xb = x + (size_t)b * CC * HH * WW + (size_t)t * WW + w;
    const float* hb = hprev + (size_t)b * hb_stride;

    for (int c = 0; c < CC; ++c) {
        float xv = xb[(size_t)c * (HH * WW)];
        const float* hc = hb + (size_t)c * hc_stride;
        float hm1 = (w > 0)      ? hc[w - 1] : 0.f;
        float h0v = hc[w];
        float hp1 = (w < WW - 1) ? hc[w + 1] : 0.f;
#pragma unroll
        for (int j = 0; j < JT; ++j) {
            int r = j0 + j;
#pragma unroll
            for (int g = 0; g < 4; ++g) {
                int row = g * NF + r;
                float a = acc[j][g];
                a = fmaf(Wm[row * CC + c], xv, a);
                const float* u = U + ((size_t)row * CC + c) * 3;
                a = fmaf(u[0], hm1, a);
                a = fmaf(u[1], h0v, a);
                a = fmaf(u[2], hp1, a);
                acc[j][g] = a;
            }
        }
    }

#pragma unroll
    for (int j = 0; j < JT; ++j) {
        float og = hsig(acc[j][0]);
        float fg = hsig(acc[j][1]);
        float ig = hsig(acc[j][2]);
        float gg = tanhf(acc[j][3]);
        size_t cidx = ((size_t)b * NF + j0 + j) * WW + w;
        float cn = fmaf(fg, c_state[cidx], ig * gg);
        c_state[cidx] = cn;
        float hn = og * tanhf(cn);
        out[((size_t)(b * NF + j0 + j) * HH + t) * WW + w] = hn;
    }
}

extern "C" void kernel_launch(void* const* d_in, const int* in_sizes, int n_in,
                              void* d_out, int out_size, void* d_ws, size_t ws_size,
                              hipStream_t stream) {
    const float* x      = (const float*)d_in[0];
    const float* W_iof  = (const float*)d_in[1];
    const float* U_iof  = (const float*)d_in[2];
    const float* b_iof  = (const float*)d_in[3];
    const float* init_h = (const float*)d_in[4];
    const float* init_c = (const float*)d_in[5];
    float* out = (float*)d_out;

    float* Wm      = (float*)d_ws;        // 768*192 floats
    float* c_state = Wm + G4 * CC;        // B*NF*W floats

    mask_weights<<<(G4 * CC + 255) / 256, 256, 0, stream>>>(W_iof, Wm);
    init_c_state<<<(BB * NF * WW + 255) / 256, 256, 0, stream>>>(init_c, c_state);

    for (int t = 0; t < HH; ++t) {
        const float* hprev = (t == 0) ? init_h : (out + (size_t)(t - 1) * WW);
        long hb = (t == 0) ? 0L : (long)NF * HH * WW;
        long hc = (t == 0) ? (long)WW : (long)HH * WW;
        lstm_step<<<dim3(NF / JT, BB), dim3(WW), 0, stream>>>(
            x, Wm, U_iof, b_iof, hprev, hb, hc, c_state, out, t);
    }
}

// Round 2
// 11502.789 us; speedup vs baseline: 4.0330x; 4.0330x over previous
//
#include <hip/hip_runtime.h>
#include <math.h>

#define BB 16
#define CC 192
#define NF 192
#define HH 128
#define WW 128
#define G4 768
#define KTOT 768
#define KC 32          // K chunk
#define LDA 40         // A LDS row stride (KC + 8 pad)
#define LDB 40         // B LDS row stride

typedef __bf16 bf16x8 __attribute__((ext_vector_type(8)));
typedef float  f32x4  __attribute__((ext_vector_type(4)));

__device__ __forceinline__ float hsig(float v) {
    float y = fmaf(0.2f, v, 0.5f);
    return fminf(fmaxf(y, 0.f), 1.f);
}

__device__ __forceinline__ unsigned short f2bf(float f) {
    unsigned int u = __float_as_uint(f);
    u += 0x7fffu + ((u >> 16) & 1u);   // round-to-nearest-even
    return (unsigned short)(u >> 16);
}

// Build combined bf16 weight matrix Wc[768][768]:
//   cols 0..191            : masked input weights Wm[row][c]
//   cols 192 + d*192 + c   : U_iof[row][c][d]  (tap-major regions, chunk-aligned)
__global__ void prep_weights(const float* __restrict__ Wf,
                             const float* __restrict__ Uf,
                             unsigned short* __restrict__ Wc) {
    int idx = blockIdx.x * blockDim.x + threadIdx.x;
    if (idx >= G4 * KTOT) return;
    int row = idx / KTOT;
    int k   = idx - row * KTOT;
    float v;
    if (k < CC) {
        int lim = row < 64 ? 64 : (row < 128 ? 128 : 192);
        v = (k < lim) ? Wf[row * CC + k] : 0.f;
    } else {
        int kp = k - CC;
        int d  = kp / CC;
        int c  = kp - d * CC;
        v = Uf[((size_t)row * CC + c) * 3 + d];
    }
    Wc[idx] = f2bf(v);
}

__global__ void init_c_state(const float* __restrict__ init_c, float* __restrict__ c_state) {
    int idx = blockIdx.x * blockDim.x + threadIdx.x;  // over B*NF*W
    if (idx >= BB * NF * WW) return;
    int jw = idx % (NF * WW);
    c_state[idx] = init_c[jw];
}

// One recurrence step t as a bf16 MFMA GEMM fused with the LSTM pointwise update.
// Block tile: M = 64 rows = {gate g in 0..3} x {16 j's}, N = 64 w's, K = 768.
// grid = (12 j-groups, 32 = b*2 + n-half); block = 128 threads (2 waves).
__global__ __launch_bounds__(128) void lstm_step_mfma(
    const float* __restrict__ x,          // (B,C,H,W) fp32
    const unsigned short* __restrict__ Wc,// (768,768) bf16
    const float* __restrict__ bias,       // (768) fp32
    const float* __restrict__ hprev, long hb, long hc_,
    float* __restrict__ c_state,          // (B,NF,W) fp32
    float* __restrict__ out,              // (B,NF,H,W) fp32
    int t)
{
    __shared__ unsigned short Alds[64][LDA];
    __shared__ unsigned short Blds[64][LDB];   // transposed: [n][k]

    const int tid  = threadIdx.x;
    const int wave = tid >> 6;
    const int lane = tid & 63;
    const int j0   = blockIdx.x * 16;
    const int nb   = blockIdx.y;
    const int b    = nb >> 1;
    const int w0   = (nb & 1) * 64;

    f32x4 acc[4][2];
#pragma unroll
    for (int g = 0; g < 4; ++g)
#pragma unroll
        for (int n = 0; n < 2; ++n)
            acc[g][n] = (f32x4){0.f, 0.f, 0.f, 0.f};

    const float* xb = x + ((size_t)b * CC * HH + t) * WW;  // + c*H*W + w
    const int wl = tid & 63;
    const int wg = w0 + wl;

    for (int kc = 0; kc < KTOT / KC; ++kc) {
        const int k0 = kc * KC;
        // --- stage A: 64 rows x 32 k (bf16), 16B vector loads ---
#pragma unroll
        for (int i = 0; i < 2; ++i) {
            int u  = tid + i * 128;          // 0..255
            int r  = u >> 2;
            int ko = (u & 3) * 8;
            int grow = (r >> 4) * NF + j0 + (r & 15);
            *(uint4*)&Alds[r][ko] =
                *(const uint4*)(Wc + (size_t)grow * KTOT + k0 + ko);
        }
        // --- stage B: 32 k-rows x 64 w, built from x or h, bf16 pairs ---
#pragma unroll
        for (int i = 0; i < 8; ++i) {
            int kp = (tid >> 6) + i * 2;     // k-pair index 0..15
            int kk = kp * 2;
            int k  = k0 + kk;
            float v0, v1;
            if (k < CC) {
                v0 = xb[(size_t)k * (HH * WW) + wg];
                v1 = xb[(size_t)(k + 1) * (HH * WW) + wg];
            } else {
                int kq = k - CC;
                int d  = kq / CC;            // uniform within chunk
                int c  = kq - d * CC;
                int wt = wg + d - 1;
                if (wt >= 0 && wt < WW) {
                    const float* hp = hprev + (size_t)b * hb + wt;
                    v0 = hp[(size_t)c * hc_];
                    v1 = hp[(size_t)(c + 1) * hc_];
                } else { v0 = 0.f; v1 = 0.f; }
            }
            unsigned int p = (unsigned int)f2bf(v0) | ((unsigned int)f2bf(v1) << 16);
            *(unsigned int*)&Blds[wl][kk] = p;
        }
        __syncthreads();

        const int m = lane & 15;
        const int q = lane >> 4;
        bf16x8 afr[4], bfr[2];
#pragma unroll
        for (int g = 0; g < 4; ++g)
            afr[g] = *(const bf16x8*)&Alds[g * 16 + m][q * 8];
#pragma unroll
        for (int n = 0; n < 2; ++n)
            bfr[n] = *(const bf16x8*)&Blds[wave * 32 + n * 16 + m][q * 8];
#pragma unroll
        for (int g = 0; g < 4; ++g)
#pragma unroll
            for (int n = 0; n < 2; ++n)
                acc[g][n] = __builtin_amdgcn_mfma_f32_16x16x32_bf16(
                    afr[g], bfr[n], acc[g][n], 0, 0, 0);
        __syncthreads();
    }

    // --- epilogue: all 4 gates for (j,w) live in this lane across acc[g] ---
    const int q   = lane >> 4;
    const int col = lane & 15;
#pragma unroll
    for (int n = 0; n < 2; ++n) {
        int w = w0 + wave * 32 + n * 16 + col;
#pragma unroll
        for (int r = 0; r < 4; ++r) {
            int j = j0 + q * 4 + r;
            float og = hsig(acc[0][n][r] + bias[0 * NF + j]);
            float fg = hsig(acc[1][n][r] + bias[1 * NF + j]);
            float ig = hsig(acc[2][n][r] + bias[2 * NF + j]);
            float gg = tanhf(acc[3][n][r] + bias[3 * NF + j]);
            size_t ci = ((size_t)b * NF + j) * WW + w;
            float cn = fmaf(fg, c_state[ci], ig * gg);
            c_state[ci] = cn;
            out[(((size_t)b * NF + j) * HH + t) * WW + w] = og * tanhf(cn);
        }
    }
}

extern "C" void kernel_launch(void* const* d_in, const int* in_sizes, int n_in,
                              void* d_out, int out_size, void* d_ws, size_t ws_size,
                              hipStream_t stream) {
    const float* x      = (const float*)d_in[0];
    const float* W_iof  = (const float*)d_in[1];
    const float* U_iof  = (const float*)d_in[2];
    const float* b_iof  = (const float*)d_in[3];
    const float* init_h = (const float*)d_in[4];
    const float* init_c = (const float*)d_in[5];
    float* out = (float*)d_out;

    unsigned short* Wc = (unsigned short*)d_ws;                 // 768*768 bf16
    float* c_state = (float*)((char*)d_ws + (size_t)G4 * KTOT * sizeof(unsigned short));

    prep_weights<<<(G4 * KTOT + 255) / 256, 256, 0, stream>>>(W_iof, U_iof, Wc);
    init_c_state<<<(BB * NF * WW + 255) / 256, 256, 0, stream>>>(init_c, c_state);

    for (int t = 0; t < HH; ++t) {
        const float* hprev = (t == 0) ? init_h : (out + (size_t)(t - 1) * WW);
        long hb = (t == 0) ? 0L : (long)NF * HH * WW;
        long hc = (t == 0) ? (long)WW : (long)HH * WW;
        lstm_step_mfma<<<dim3(NF / 16, BB * 2), dim3(128), 0, stream>>>(
            x, Wc, b_iof, hprev, hb, hc, c_state, out, t);
    }
}

// Round 3
// 5132.062 us; speedup vs baseline: 9.0394x; 2.2414x over previous
//
#include <hip/hip_runtime.h>
#include <hip/hip_cooperative_groups.h>
#include <math.h>

namespace cg = cooperative_groups;

#define BB 16
#define CC 192
#define NF 192
#define HH 128
#define WW 128
#define G4 768
#define KTOT 768
#define LDA 776                 // A LDS row stride in shorts (768 + 8 pad)
#define NJB 12                  // j-blocks (NF/16)
#define GRIDSZ (NJB * BB)       // 192 blocks
#define SMEM_BYTES ((64 * LDA + 128 * 24) * 2)

typedef __bf16 bf16x8 __attribute__((ext_vector_type(8)));
typedef float  f32x4  __attribute__((ext_vector_type(4)));

__device__ __forceinline__ float hsig(float v) {
    float y = fmaf(0.2f, v, 0.5f);
    return fminf(fmaxf(y, 0.f), 1.f);
}

__device__ __forceinline__ unsigned short f2bf(float f) {
    unsigned int u = __float_as_uint(f);
    u += 0x7fffu + ((u >> 16) & 1u);   // RNE
    return (unsigned short)(u >> 16);
}

// Wc[row=g*NF+j][k]: k<192 masked input weights; k=192+d*192+c = U tap d.
__global__ void prep_weights(const float* __restrict__ Wf,
                             const float* __restrict__ Uf,
                             unsigned short* __restrict__ Wc) {
    int idx = blockIdx.x * blockDim.x + threadIdx.x;
    if (idx >= G4 * KTOT) return;
    int row = idx / KTOT;
    int k   = idx - row * KTOT;
    float v;
    if (k < CC) {
        int lim = row < 64 ? 64 : (row < 128 ? 128 : 192);
        v = (k < lim) ? Wf[row * CC + k] : 0.f;
    } else {
        int kp = k - CC;
        int d  = kp / CC;
        int c  = kp - d * CC;
        v = Uf[((size_t)row * CC + c) * 3 + d];
    }
    Wc[idx] = f2bf(v);
}

// x-part of Bsrc: Bsrc[t][b][w][c] = bf16(x[b][c][t][w]), c in [0,192).
__global__ void prep_bx(const float* __restrict__ x, unsigned short* __restrict__ Bsrc) {
    int idx = blockIdx.x * blockDim.x + threadIdx.x;   // over 128*16*128
    if (idx >= HH * BB * WW) return;
    int w = idx & (WW - 1);
    int r = idx >> 7;
    int b = r & (BB - 1);
    int t = r >> 4;
    const float* xp = x + ((size_t)b * CC * HH + t) * WW + w;
    unsigned short* dp = Bsrc + (size_t)idx * KTOT;
#pragma unroll
    for (int cc = 0; cc < CC / 8; ++cc) {
        unsigned short v[8];
#pragma unroll
        for (int i = 0; i < 8; ++i)
            v[i] = f2bf(xp[(size_t)(cc * 8 + i) * (HH * WW)]);
        *(uint4*)(dp + cc * 8) = *(uint4*)v;
    }
}

// Zero the never-written halo slots for all t: [t][b][0][192..384) and [t][b][127][576..768).
__global__ void prep_bh_oob(unsigned short* __restrict__ Bsrc) {
    int idx = blockIdx.x * blockDim.x + threadIdx.x;   // 128*16*384
    if (idx >= HH * BB * 384) return;
    int u = idx % 384;
    int r = idx / 384;
    int b = r & (BB - 1);
    int t = r >> 4;
    size_t base = ((size_t)(t * BB + b) * WW) * KTOT;
    size_t off = (u < 192) ? (size_t)0 * KTOT + 192 + u
                           : (size_t)127 * KTOT + 384 + u;   // 576 + (u-192)
    Bsrc[base + off] = 0;
}

// t=0 h-part from init_h: Bsrc[0][b][w][192+d*192+c] = init_h[c][w+d-1] (0 if OOB).
__global__ void prep_bh0(const float* __restrict__ init_h, unsigned short* __restrict__ Bsrc) {
    int idx = blockIdx.x * blockDim.x + threadIdx.x;   // 16*128*576
    if (idx >= BB * WW * 576) return;
    int kp = idx % 576;
    int r  = idx / 576;
    int w  = r & (WW - 1);
    int b  = r >> 7;
    int d  = kp / CC;
    int c  = kp - d * CC;
    int wt = w + d - 1;
    float v = (wt >= 0 && wt < WW) ? init_h[c * WW + wt] : 0.f;
    Bsrc[((size_t)b * WW + w) * KTOT + CC + kp] = f2bf(v);
}

// Persistent LSTM: all 128 steps, grid-synced. 192 blocks x 256 threads.
// Block = (j-tile of 16, batch b); M=64 rows (4 gates x 16 j), N=128 (all w).
__global__ __launch_bounds__(256, 1) void lstm_persist(
    const unsigned short* __restrict__ Wc,
    unsigned short* __restrict__ Bsrc,
    const float* __restrict__ bias,
    const float* __restrict__ init_c,
    float* __restrict__ out)
{
    extern __shared__ unsigned short smem[];
    unsigned short (*Alds)[LDA] = (unsigned short(*)[LDA])smem;
    unsigned short (*hT)[24]    = (unsigned short(*)[24])(smem + 64 * LDA);

    cg::grid_group grid = cg::this_grid();
    const int tid  = threadIdx.x;
    const int wave = tid >> 6;
    const int lane = tid & 63;
    const int m    = lane & 15;
    const int q    = lane >> 4;
    const int jb   = blockIdx.x % NJB;
    const int b    = blockIdx.x / NJB;
    const int j0   = jb * 16;

    // ---- load A once: row r -> Wc row (r>>4)*NF + j0 + (r&15) ----
    for (int u = tid; u < 64 * 96; u += 256) {
        int r  = u / 96;
        int ko = (u - r * 96) * 8;
        int grow = (r >> 4) * NF + j0 + (r & 15);
        *(uint4*)&Alds[r][ko] = *(const uint4*)(Wc + (size_t)grow * KTOT + ko);
    }
    // ---- bias & c-state in registers ----
    float breg[4][4];
#pragma unroll
    for (int g = 0; g < 4; ++g)
#pragma unroll
        for (int r = 0; r < 4; ++r)
            breg[g][r] = bias[g * NF + j0 + q * 4 + r];
    float creg[2][4];
#pragma unroll
    for (int n = 0; n < 2; ++n)
#pragma unroll
        for (int r = 0; r < 4; ++r)
            creg[n][r] = init_c[(j0 + q * 4 + r) * WW + wave * 32 + n * 16 + m];
    __syncthreads();

    for (int t = 0; t < HH; ++t) {
        f32x4 acc[4][2];
#pragma unroll
        for (int g = 0; g < 4; ++g)
#pragma unroll
            for (int n = 0; n < 2; ++n)
                acc[g][n] = (f32x4){breg[g][0], breg[g][1], breg[g][2], breg[g][3]};

        const unsigned short* Bb  = Bsrc + ((size_t)(t * BB + b) * WW) * KTOT;
        const unsigned short* Bn0 = Bb + (size_t)(wave * 32 + m) * KTOT;
        const unsigned short* Bn1 = Bn0 + (size_t)16 * KTOT;

#pragma unroll 8
        for (int kc = 0; kc < KTOT / 32; ++kc) {
            const int k = kc * 32 + q * 8;
            bf16x8 b0 = *(const bf16x8*)(Bn0 + k);
            bf16x8 b1 = *(const bf16x8*)(Bn1 + k);
            bf16x8 a0 = *(const bf16x8*)&Alds[ 0 + m][k];
            bf16x8 a1 = *(const bf16x8*)&Alds[16 + m][k];
            bf16x8 a2 = *(const bf16x8*)&Alds[32 + m][k];
            bf16x8 a3 = *(const bf16x8*)&Alds[48 + m][k];
            acc[0][0] = __builtin_amdgcn_mfma_f32_16x16x32_bf16(a0, b0, acc[0][0], 0, 0, 0);
            acc[0][1] = __builtin_amdgcn_mfma_f32_16x16x32_bf16(a0, b1, acc[0][1], 0, 0, 0);
            acc[1][0] = __builtin_amdgcn_mfma_f32_16x16x32_bf16(a1, b0, acc[1][0], 0, 0, 0);
            acc[1][1] = __builtin_amdgcn_mfma_f32_16x16x32_bf16(a1, b1, acc[1][1], 0, 0, 0);
            acc[2][0] = __builtin_amdgcn_mfma_f32_16x16x32_bf16(a2, b0, acc[2][0], 0, 0, 0);
            acc[2][1] = __builtin_amdgcn_mfma_f32_16x16x32_bf16(a2, b1, acc[2][1], 0, 0, 0);
            acc[3][0] = __builtin_amdgcn_mfma_f32_16x16x32_bf16(a3, b0, acc[3][0], 0, 0, 0);
            acc[3][1] = __builtin_amdgcn_mfma_f32_16x16x32_bf16(a3, b1, acc[3][1], 0, 0, 0);
        }

        // ---- epilogue: gates + c/h update, h -> LDS transpose ----
#pragma unroll
        for (int n = 0; n < 2; ++n) {
            const int w = wave * 32 + n * 16 + m;
#pragma unroll
            for (int r = 0; r < 4; ++r) {
                const int j = j0 + q * 4 + r;
                float og = hsig(acc[0][n][r]);
                float fg = hsig(acc[1][n][r]);
                float ig = hsig(acc[2][n][r]);
                float gg = tanhf(acc[3][n][r]);
                float cn = fmaf(fg, creg[n][r], ig * gg);
                creg[n][r] = cn;
                float hn = og * tanhf(cn);
                out[(((size_t)b * NF + j) * HH + t) * WW + w] = hn;
                hT[w][q * 4 + r] = f2bf(hn);
            }
        }
        __syncthreads();

        // ---- scatter h into next step's B source (coalesced 16B runs) ----
        if (t < HH - 1) {
            unsigned short* Bn = Bsrc + ((size_t)((t + 1) * BB + b) * WW) * KTOT;
            for (int u = tid; u < 384; u += 256) {
                int d  = u >> 7;
                int w2 = u & 127;
                int w  = w2 + d - 1;
                if (w >= 0 && w < WW) {
                    uint4 lo = *(uint4*)&hT[w][0];
                    uint4 hi = *(uint4*)&hT[w][8];
                    unsigned short* dst = Bn + (size_t)w2 * KTOT + CC + d * CC + j0;
                    *(uint4*)dst       = lo;
                    *(uint4*)(dst + 8) = hi;
                }
            }
        }
        grid.sync();
    }
}

extern "C" void kernel_launch(void* const* d_in, const int* in_sizes, int n_in,
                              void* d_out, int out_size, void* d_ws, size_t ws_size,
                              hipStream_t stream) {
    const float* x      = (const float*)d_in[0];
    const float* W_iof  = (const float*)d_in[1];
    const float* U_iof  = (const float*)d_in[2];
    const float* b_iof  = (const float*)d_in[3];
    const float* init_h = (const float*)d_in[4];
    const float* init_c = (const float*)d_in[5];
    float* out = (float*)d_out;

    unsigned short* Wc   = (unsigned short*)d_ws;                       // 768*768 bf16
    unsigned short* Bsrc = Wc + (size_t)G4 * KTOT;                      // 128*16*128*768 bf16

    prep_weights<<<(G4 * KTOT + 255) / 256, 256, 0, stream>>>(W_iof, U_iof, Wc);
    prep_bx<<<(HH * BB * WW + 255) / 256, 256, 0, stream>>>(x, Bsrc);
    prep_bh_oob<<<(HH * BB * 384 + 255) / 256, 256, 0, stream>>>(Bsrc);
    prep_bh0<<<(BB * WW * 576 + 255) / 256, 256, 0, stream>>>(init_h, Bsrc);

    const unsigned short* Wcp = Wc;
    unsigned short* Bsp = Bsrc;
    const float* bp = b_iof;
    const float* icp = init_c;
    float* op = out;
    void* args[] = {&Wcp, &Bsp, &bp, &icp, &op};
    hipLaunchCooperativeKernel((const void*)lstm_persist, dim3(GRIDSZ), dim3(256),
                               args, SMEM_BYTES, stream);
}